// Round 3
// baseline (64570.673 us; speedup 1.0000x reference)
//
#include <hip/hip_runtime.h>
#include <hip/hip_bf16.h>
#include <math.h>

// ws layout (floats)
#define H0_OFF   0          // [2][64][512]
#define H1_OFF   65536      // [2][64][512]
#define RH0_OFF  131072     // [64][512]
#define RH1_OFF  163840     // [64][512]
#define CTR_FLT  196608     // counters (ints) after this
#define WS_BYTES (786432 + 8*256)

__device__ __forceinline__ float gload(const float* p) {
    return __hip_atomic_load(p, __ATOMIC_RELAXED, __HIP_MEMORY_SCOPE_AGENT);
}
__device__ __forceinline__ void gstore(float* p, float v) {
    __hip_atomic_store(p, v, __ATOMIC_RELAXED, __HIP_MEMORY_SCOPE_AGENT);
}
__device__ __forceinline__ float sigm(float x) { return 1.f / (1.f + expf(-x)); }

__device__ __forceinline__ void fma8_2(float4 w1, float4 w2,
                                       const float* __restrict__ S, int srow, int k,
                                       float aR[8], float aZ[8]) {
    #pragma unroll
    for (int b = 0; b < 8; ++b) {
        float4 xv = *(const float4*)(S + b * srow + k);
        aR[b] = fmaf(w1.x, xv.x, fmaf(w1.y, xv.y, fmaf(w1.z, xv.z, fmaf(w1.w, xv.w, aR[b]))));
        aZ[b] = fmaf(w2.x, xv.x, fmaf(w2.y, xv.y, fmaf(w2.z, xv.z, fmaf(w2.w, xv.w, aZ[b]))));
    }
}
__device__ __forceinline__ void fma8_1(float4 w1,
                                       const float* __restrict__ S, int srow, int k,
                                       float aH[8]) {
    #pragma unroll
    for (int b = 0; b < 8; ++b) {
        float4 xv = *(const float4*)(S + b * srow + k);
        aH[b] = fmaf(w1.x, xv.x, fmaf(w1.y, xv.y, fmaf(w1.z, xv.z, fmaf(w1.w, xv.w, aH[b]))));
    }
}

__device__ __forceinline__ void butterfly8(float v[8]) {
    #pragma unroll
    for (int m = 4; m >= 1; m >>= 1) {
        #pragma unroll
        for (int b = 0; b < 8; ++b) v[b] += __shfl_xor(v[b], m, 64);
    }
}
__device__ __forceinline__ float pick8(const float v[8], int p) {
    float r = v[0];
    #pragma unroll
    for (int b = 1; b < 8; ++b) if (p == b) r = v[b];
    return r;
}

__device__ __forceinline__ void domain_barrier(int* ctr, int target) {
    __syncthreads();
    if (threadIdx.x == 0) {
        __hip_atomic_fetch_add(ctr, 1, __ATOMIC_RELEASE, __HIP_MEMORY_SCOPE_AGENT);
        while (__hip_atomic_load(ctr, __ATOMIC_RELAXED, __HIP_MEMORY_SCOPE_AGENT) < target)
            __builtin_amdgcn_s_sleep(1);
    }
    __syncthreads();
}

__global__ __launch_bounds__(256, 1) void gru_main(
    const int* __restrict__ tokens, const float* __restrict__ emb,
    const float* __restrict__ Wr0, const float* __restrict__ br0,
    const float* __restrict__ Wz0, const float* __restrict__ bz0,
    const float* __restrict__ Wh0, const float* __restrict__ bh0,
    const float* __restrict__ Wr1, const float* __restrict__ br1,
    const float* __restrict__ Wz1, const float* __restrict__ bz1,
    const float* __restrict__ Wh1, const float* __restrict__ bh1,
    float* __restrict__ ws)
{
    const int blk = blockIdx.x;
    // g = blk&7: all 32 wgs of a batch-group land on ONE XCD (round-robin %8,
    // confirmed by R2's FETCH staying L2-resident). State + barrier = XCD-local.
    const int g = blk & 7;
    const int j = blk >> 3;       // column slice 0..31
    const int tid = threadIdx.x;
    const int layer = tid >> 7;   // 0 or 1 (wave-uniform)
    const int lt = tid & 127;
    const int w = lt >> 6;        // wave within layer
    const int lane = lt & 63;
    const int cg = lane >> 3;     // col within wave
    const int p8 = lane & 7;      // k-slice; owns batch row p8 after reduce
    const int c = j * 16 + w * 8 + cg;
    const int koff = 4 * p8;
    const int bg = g * 8 + p8;

    float* h0buf = ws + H0_OFF;
    float* h1buf = ws + H1_OFF;
    float* rh0 = ws + RH0_OFF;
    float* rh1 = ws + RH1_OFF;
    int* ctr = (int*)(ws + CTR_FLT) + g * 64;

    const int K = layer ? 1024 : 768;
    const float* wrRow = (layer ? Wr1 : Wr0) + (size_t)c * K;
    const float* wzRow = (layer ? Wz1 : Wz0) + (size_t)c * K;
    const float* whRow = (layer ? Wh1 : Wh0) + (size_t)c * K;
    const float bR = (layer ? br1 : br0)[c];
    const float bZ = (layer ? bz1 : bz0)[c];
    const float bH = (layer ? bh1 : bh0)[c];

    // LDS: state staging (flat, conflict-free) + L1 h-gate weights (lane-consecutive)
    __shared__ float sx[2048];       // x_t   [8][256]
    __shared__ float sh0[4096];      // h0 prev [8][512]
    __shared__ float sh1[4096];      // h1 prev [8][512]
    __shared__ float sr0[4096];      // rh0 [8][512]
    __shared__ float sr1[4096];      // rh1 [8][512]
    __shared__ float4 whL1[4096];    // 64 KB: [w][i 0..31][lane] lane-consecutive

    // ---- one-time weight preload: registers (+ LDS for L1 h-gate) ----
    // L0: wr=[0..7]+[8..23], wz=[24..31]+[32..47], wh=[48..55]+[56..71]
    // L1: wr=[0..15]+[16..31], wz=[32..47]+[48..63]
    float4 wReg[72];
    if (layer == 0) {
        #pragma unroll
        for (int i = 0; i < 8; ++i)  wReg[i]      = *(const float4*)(wrRow + koff + 32 * i);
        #pragma unroll
        for (int i = 0; i < 16; ++i) wReg[8 + i]  = *(const float4*)(wrRow + 256 + koff + 32 * i);
        #pragma unroll
        for (int i = 0; i < 8; ++i)  wReg[24 + i] = *(const float4*)(wzRow + koff + 32 * i);
        #pragma unroll
        for (int i = 0; i < 16; ++i) wReg[32 + i] = *(const float4*)(wzRow + 256 + koff + 32 * i);
        #pragma unroll
        for (int i = 0; i < 8; ++i)  wReg[48 + i] = *(const float4*)(whRow + koff + 32 * i);
        #pragma unroll
        for (int i = 0; i < 16; ++i) wReg[56 + i] = *(const float4*)(whRow + 256 + koff + 32 * i);
    } else {
        #pragma unroll
        for (int i = 0; i < 16; ++i) wReg[i]      = *(const float4*)(wrRow + koff + 32 * i);
        #pragma unroll
        for (int i = 0; i < 16; ++i) wReg[16 + i] = *(const float4*)(wrRow + 512 + koff + 32 * i);
        #pragma unroll
        for (int i = 0; i < 16; ++i) wReg[32 + i] = *(const float4*)(wzRow + koff + 32 * i);
        #pragma unroll
        for (int i = 0; i < 16; ++i) wReg[48 + i] = *(const float4*)(wzRow + 512 + koff + 32 * i);
        float4 z4 = {0.f, 0.f, 0.f, 0.f};
        #pragma unroll
        for (int i = 64; i < 72; ++i) wReg[i] = z4;
        #pragma unroll
        for (int i = 0; i < 16; ++i)
            whL1[(w * 32 + i) * 64 + lane] = *(const float4*)(whRow + koff + 32 * i);
        #pragma unroll
        for (int i = 0; i < 16; ++i)
            whL1[(w * 32 + 16 + i) * 64 + lane] = *(const float4*)(whRow + 512 + koff + 32 * i);
    }

    int target = 32;
    for (int s = 0; s <= 1024; ++s) {
        const int rd0 = (s & 1) ^ 1;   // h0 read slot
        // ---- P1 staging: lane-coalesced flat copies ----
        {
            const float* src0 = h0buf + rd0 * 32768 + g * 4096;
            const float* src1 = h1buf + (s & 1) * 32768 + g * 4096;
            #pragma unroll
            for (int q = 0; q < 16; ++q) sh0[tid + 256 * q] = gload(src0 + tid + 256 * q);
            #pragma unroll
            for (int q = 0; q < 16; ++q) sh1[tid + 256 * q] = gload(src1 + tid + 256 * q);
            if (s < 1024) {
                #pragma unroll
                for (int q = 0; q < 8; ++q) {
                    int tok = tokens[(g * 8 + q) * 1024 + s];
                    sx[tid + 256 * q] = emb[(size_t)tok * 256 + tid];
                }
            }
        }
        __syncthreads();

        const bool act = layer ? (s >= 1) : (s < 1024);
        float zv = 0.f, hp = 0.f;
        if (act) {
            float aR[8] = {0,0,0,0,0,0,0,0}, aZ[8] = {0,0,0,0,0,0,0,0};
            if (layer == 0) {
                #pragma unroll
                for (int i = 0; i < 8; ++i)
                    fma8_2(wReg[i], wReg[24 + i], sx, 256, koff + 32 * i, aR, aZ);
                #pragma unroll
                for (int i = 0; i < 16; ++i)
                    fma8_2(wReg[8 + i], wReg[32 + i], sh0, 512, koff + 32 * i, aR, aZ);
            } else {
                #pragma unroll
                for (int i = 0; i < 16; ++i)
                    fma8_2(wReg[i], wReg[32 + i], sh0, 512, koff + 32 * i, aR, aZ);
                #pragma unroll
                for (int i = 0; i < 16; ++i)
                    fma8_2(wReg[16 + i], wReg[48 + i], sh1, 512, koff + 32 * i, aR, aZ);
            }
            butterfly8(aR);
            butterfly8(aZ);
            float rv = sigm(pick8(aR, p8) + bR);
            zv = sigm(pick8(aZ, p8) + bZ);
            hp = layer ? sh1[p8 * 512 + c] : sh0[p8 * 512 + c];
            float* rhb = layer ? rh1 : rh0;
            gstore(rhb + bg * 512 + c, rv * hp);
        }
        domain_barrier(ctr, target); target += 32;

        // ---- P2 staging ----
        {
            const float* src0 = rh0 + g * 4096;
            const float* src1 = rh1 + g * 4096;
            #pragma unroll
            for (int q = 0; q < 16; ++q) sr0[tid + 256 * q] = gload(src0 + tid + 256 * q);
            #pragma unroll
            for (int q = 0; q < 16; ++q) sr1[tid + 256 * q] = gload(src1 + tid + 256 * q);
        }
        __syncthreads();

        if (act) {
            float aH[8] = {0,0,0,0,0,0,0,0};
            if (layer == 0) {
                #pragma unroll
                for (int i = 0; i < 8; ++i)
                    fma8_1(wReg[48 + i], sx, 256, koff + 32 * i, aH);
                #pragma unroll
                for (int i = 0; i < 16; ++i)
                    fma8_1(wReg[56 + i], sr0, 512, koff + 32 * i, aH);
            } else {
                #pragma unroll
                for (int i = 0; i < 16; ++i)
                    fma8_1(whL1[(w * 32 + i) * 64 + lane], sh0, 512, koff + 32 * i, aH);
                #pragma unroll
                for (int i = 0; i < 16; ++i)
                    fma8_1(whL1[(w * 32 + 16 + i) * 64 + lane], sr1, 512, koff + 32 * i, aH);
            }
            butterfly8(aH);
            float ht = tanhf(pick8(aH, p8) + bH);
            float hn = (1.f - zv) * hp + zv * ht;
            float* hb = layer ? (h1buf + ((s - 1) & 1) * 32768)
                              : (h0buf + (s & 1) * 32768);
            gstore(hb + bg * 512 + c, hn);
        }
        domain_barrier(ctr, target); target += 32;
    }
}

__global__ __launch_bounds__(128) void gru_fc(
    const float* __restrict__ h1f, const float* __restrict__ fcW,
    const float* __restrict__ fcb, float* __restrict__ out)
{
    int tid = threadIdx.x;
    int b = tid >> 1, cc = tid & 1;
    const float* hrow = h1f + b * 512;
    const float* wrow = fcW + cc * 512;
    float acc = 0.f;
    #pragma unroll 4
    for (int k = 0; k < 512; k += 4) {
        float4 hv = *(const float4*)(hrow + k);
        float4 wv = *(const float4*)(wrow + k);
        acc = fmaf(hv.x, wv.x, fmaf(hv.y, wv.y, fmaf(hv.z, wv.z, fmaf(hv.w, wv.w, acc))));
    }
    out[b * 2 + cc] = acc + fcb[cc];
}

extern "C" void kernel_launch(void* const* d_in, const int* in_sizes, int n_in,
                              void* d_out, int out_size, void* d_ws, size_t ws_size,
                              hipStream_t stream) {
    const int* tokens = (const int*)d_in[0];
    const float* emb = (const float*)d_in[1];
    const float* Wr0 = (const float*)d_in[2];  const float* br0 = (const float*)d_in[3];
    const float* Wz0 = (const float*)d_in[4];  const float* bz0 = (const float*)d_in[5];
    const float* Wh0 = (const float*)d_in[6];  const float* bh0 = (const float*)d_in[7];
    const float* Wr1 = (const float*)d_in[8];  const float* br1 = (const float*)d_in[9];
    const float* Wz1 = (const float*)d_in[10]; const float* bz1 = (const float*)d_in[11];
    const float* Wh1 = (const float*)d_in[12]; const float* bh1 = (const float*)d_in[13];
    const float* fcW = (const float*)d_in[14]; const float* fcb = (const float*)d_in[15];
    float* ws = (float*)d_ws;

    hipMemsetAsync(d_ws, 0, WS_BYTES, stream);

    gru_main<<<256, 256, 0, stream>>>(tokens, emb, Wr0, br0, Wz0, bz0, Wh0, bh0,
                                      Wr1, br1, Wz1, bz1, Wh1, bh1, ws);
    // final hidden state of layer 1: t=1023 -> slot 1
    gru_fc<<<1, 128, 0, stream>>>(ws + H1_OFF + 32768, fcW, fcb, (float*)d_out);
}

// Round 5
// 40782.224 us; speedup vs baseline: 1.5833x; 1.5833x over previous
//
#include <hip/hip_runtime.h>
#include <hip/hip_bf16.h>
#include <math.h>

// ws layout (floats)
#define H0_OFF   0            // [64][512]
#define H1_OFF   32768        // [64][512]
#define RH0_OFF  65536        // [64][512]
#define RH1_OFF  98304        // [64][512]
#define FLG_OFF  131072       // u32[2 domains][128 slots]
#define WS_FLOATS (131072 + 256)
#define WS_BYTES  (WS_FLOATS * 4)

// LDS row stride (words). 524 % 32 == 12: the 8 rgl-lanes (rows ri = rgl+8*rr)
// map to 8 distinct bank-quads (12*rgl mod 32 covers {0,4,..,28}) -> b128
// state reads are conflict-free. 524 % 4 == 0 keeps 16B alignment.
#define SROW 524

__device__ __forceinline__ float gload(const float* p) {
    return __hip_atomic_load(p, __ATOMIC_RELAXED, __HIP_MEMORY_SCOPE_AGENT);
}
__device__ __forceinline__ void gstore(float* p, float v) {
    __hip_atomic_store(p, v, __ATOMIC_RELAXED, __HIP_MEMORY_SCOPE_AGENT);
}
__device__ __forceinline__ float2 gload2(const float* p) {
    unsigned long long u = __hip_atomic_load((const unsigned long long*)p,
                                             __ATOMIC_RELAXED, __HIP_MEMORY_SCOPE_AGENT);
    return __builtin_bit_cast(float2, u);
}
__device__ __forceinline__ unsigned gloadU(const unsigned* p) {
    return __hip_atomic_load(p, __ATOMIC_RELAXED, __HIP_MEMORY_SCOPE_AGENT);
}
__device__ __forceinline__ void gstoreU(unsigned* p, unsigned v) {
    __hip_atomic_store(p, v, __ATOMIC_RELAXED, __HIP_MEMORY_SCOPE_AGENT);
}
__device__ __forceinline__ float fma4(float4 w, float4 x, float a) {
    a = fmaf(w.x, x.x, a); a = fmaf(w.y, x.y, a);
    a = fmaf(w.z, x.z, a); a = fmaf(w.w, x.w, a);
    return a;
}

// RMW-free barrier over one 128-wg domain: arrival = one u32 store,
// wait = wave0 polls all 128 flags. MONOTONE comparison (>=): a fast wg may
// already have advanced its slot to tag+1; equality-compare deadlocks (R4 bug).
__device__ __forceinline__ void flag_barrier(unsigned* flags, int slot, int tid, unsigned tag) {
    __syncthreads();
    if (tid == 0) gstoreU(flags + slot, tag);
    if (tid < 64) {
        for (;;) {
            unsigned v0 = gloadU(flags + tid);
            unsigned v1 = gloadU(flags + 64 + tid);
            bool ok = ((int)(v0 - tag) >= 0) && ((int)(v1 - tag) >= 0);
            if (__ballot(ok) == ~0ull) break;
            __builtin_amdgcn_s_sleep(1);
        }
    }
    __syncthreads();
}

__global__ __launch_bounds__(256, 1) void gru_main(
    const int* __restrict__ tokens, const float* __restrict__ emb,
    const float* __restrict__ Wr0, const float* __restrict__ br0,
    const float* __restrict__ Wz0, const float* __restrict__ bz0,
    const float* __restrict__ Wh0, const float* __restrict__ bh0,
    const float* __restrict__ Wr1, const float* __restrict__ br1,
    const float* __restrict__ Wz1, const float* __restrict__ bz1,
    const float* __restrict__ Wh1, const float* __restrict__ bh1,
    float* __restrict__ ws)
{
    const int blk   = blockIdx.x;
    // XCD = blk%8 = rg*4 + jl. Per XCD: fixed (rg, jl) -> 32 wgs (2 layers x 16 jh),
    // weight footprint 2.75 MB < 4 MB L2-resident; domain rg spans XCDs {4rg..4rg+3}.
    const int rg    = (blk >> 2) & 1;
    const int jl    = blk & 3;
    const int jh    = (blk >> 3) & 15;
    const int layer = blk >> 7;
    const int j     = jh * 4 + jl;            // 0..63 col slice (8 cols)
    const int tid   = threadIdx.x;
    const int ks    = tid >> 6;               // k-slice (wave)
    const int lane  = tid & 63;
    const int c     = lane >> 3;              // 0..7 col within slice
    const int rgl   = lane & 7;               // row-lane; rows ri = rgl + 8*rr
    const int rowbase = rg * 32;
    const int cg    = j * 8 + c;              // global col (compute role)
    // reducer role: thread t -> (cR, riR)
    const int cR    = tid >> 5;               // 0..7
    const int riR   = tid & 31;               // 0..31
    const int cgR   = j * 8 + cR;

    const int S1 = layer ? 512 : 256;
    const int K  = S1 + 512;
    const float* WrL = layer ? Wr1 : Wr0;
    const float* WzL = layer ? Wz1 : Wz0;
    const float* WhL = layer ? Wh1 : Wh0;
    const float* wrRow = WrL + (size_t)cg * K;
    const float* wzRow = WzL + (size_t)cg * K;
    const float* whRow = WhL + (size_t)cg * K;
    const float bR = (layer ? br1 : br0)[cgR];
    const float bZ = (layer ? bz1 : bz0)[cgR];
    const float bH = (layer ? bh1 : bh0)[cgR];

    float* hOwn  = ws + (layer ? H1_OFF : H0_OFF);
    float* rhOwn = ws + (layer ? RH1_OFF : RH0_OFF);
    const float* hIn = ws + H0_OFF;           // L1 seg1 source (h0_t)
    unsigned* flags = (unsigned*)(ws + FLG_OFF) + rg * 128;
    const int slot = (layer * 16 + jh) * 4 + jl;   // 0..127 in domain

    __shared__ float bufA[32 * SROW];   // seg1 (x or h0_t), then rh in P2
    __shared__ float bufB[32 * SROW];   // own-layer h_prev
    __shared__ float pTmp[3 * 4 * 256]; // partials [gate][ks][c*32+ri]

    const int q1  = S1 >> 2;            // seg1 slice len per wave (64 / 128)
    const int k1  = ks * q1;            // seg1 base
    const int k2  = S1 + ks * 128;      // seg2 base (weight coords)
    const int k2s = ks * 128;           // seg2 base (state coords)

    for (int s = 0; s <= 1024; ++s) {
        const bool act = layer ? (s >= 1) : (s < 1024);
        float zv = 0.f, hp = 0.f, hx = 0.f;

        if (act) {
            // ---- P1 staging: bufB = own h_prev rows; bufA = seg1 ----
            {
                const float* src = hOwn + rowbase * 512;
                #pragma unroll 8
                for (int q = 0; q < 32; ++q) {
                    int f2i = tid + 256 * q;            // 0..8191
                    int row = f2i >> 8, col2 = f2i & 255;
                    float2 v = gload2(src + f2i * 2);
                    *(float2*)&bufB[row * SROW + col2 * 2] = v;
                }
            }
            if (layer) {
                const float* src = hIn + rowbase * 512;
                #pragma unroll 8
                for (int q = 0; q < 32; ++q) {
                    int f2i = tid + 256 * q;
                    int row = f2i >> 8, col2 = f2i & 255;
                    float2 v = gload2(src + f2i * 2);
                    *(float2*)&bufA[row * SROW + col2 * 2] = v;
                }
            } else {
                #pragma unroll
                for (int q = 0; q < 8; ++q) {
                    int f4i = tid + 256 * q;            // 0..2047
                    int row = f4i >> 6, col4 = f4i & 63;
                    int tok = tokens[(rowbase + row) * 1024 + s];
                    float4 v = *(const float4*)(emb + (size_t)tok * 256 + col4 * 4);
                    *(float4*)&bufA[row * SROW + col4 * 4] = v;
                }
            }
            __syncthreads();

            // ---- P1 dots: r,z over seg1+seg2; h x-part over seg1 ----
            float aR[4] = {0,0,0,0}, aZ[4] = {0,0,0,0}, aH[4] = {0,0,0,0};
            const int nq1 = q1 >> 2;
            #pragma unroll 4
            for (int i = 0; i < nq1; ++i) {
                int kk = k1 + 4 * i;
                float4 w1 = *(const float4*)(wrRow + kk);
                float4 w2 = *(const float4*)(wzRow + kk);
                float4 w3 = *(const float4*)(whRow + kk);
                #pragma unroll
                for (int rr = 0; rr < 4; ++rr) {
                    float4 xv = *(const float4*)(&bufA[(rgl + 8 * rr) * SROW + kk]);
                    aR[rr] = fma4(w1, xv, aR[rr]);
                    aZ[rr] = fma4(w2, xv, aZ[rr]);
                    aH[rr] = fma4(w3, xv, aH[rr]);
                }
            }
            #pragma unroll 4
            for (int i = 0; i < 32; ++i) {
                int kw = k2 + 4 * i, kst = k2s + 4 * i;
                float4 w1 = *(const float4*)(wrRow + kw);
                float4 w2 = *(const float4*)(wzRow + kw);
                #pragma unroll
                for (int rr = 0; rr < 4; ++rr) {
                    float4 xv = *(const float4*)(&bufB[(rgl + 8 * rr) * SROW + kst]);
                    aR[rr] = fma4(w1, xv, aR[rr]);
                    aZ[rr] = fma4(w2, xv, aZ[rr]);
                }
            }
            #pragma unroll
            for (int rr = 0; rr < 4; ++rr) {
                int o = ks * 256 + c * 32 + (rgl + 8 * rr);
                pTmp[o]        = aR[rr];
                pTmp[1024 + o] = aZ[rr];
                pTmp[2048 + o] = aH[rr];
            }
            __syncthreads();

            // ---- P1 reduce + activations (thread t owns (cR, riR)) ----
            int o = cR * 32 + riR;
            float sR = pTmp[o] + pTmp[o + 256] + pTmp[o + 512] + pTmp[o + 768];
            float sZ = pTmp[1024 + o] + pTmp[1280 + o] + pTmp[1536 + o] + pTmp[1792 + o];
            float sH = pTmp[2048 + o] + pTmp[2304 + o] + pTmp[2560 + o] + pTmp[2816 + o];
            float rv = 1.f / (1.f + expf(-(sR + bR)));
            zv = 1.f / (1.f + expf(-(sZ + bZ)));
            hx = sH;
            hp = bufB[riR * SROW + cgR];      // own h_prev[row, col]
            gstore(rhOwn + (rowbase + riR) * 512 + cgR, rv * hp);
        }

        flag_barrier(flags, slot, tid, (unsigned)(2 * s + 1));

        if (act) {
            // ---- P2 staging: bufA = rh rows ----
            const float* src = rhOwn + rowbase * 512;
            #pragma unroll 8
            for (int q = 0; q < 32; ++q) {
                int f2i = tid + 256 * q;
                int row = f2i >> 8, col2 = f2i & 255;
                float2 v = gload2(src + f2i * 2);
                *(float2*)&bufA[row * SROW + col2 * 2] = v;
            }
            __syncthreads();

            // ---- P2 dot: h-gate recurrent over seg2 ----
            float a[4] = {0,0,0,0};
            #pragma unroll 4
            for (int i = 0; i < 32; ++i) {
                int kw = k2 + 4 * i, kst = k2s + 4 * i;
                float4 w3 = *(const float4*)(whRow + kw);
                #pragma unroll
                for (int rr = 0; rr < 4; ++rr) {
                    float4 xv = *(const float4*)(&bufA[(rgl + 8 * rr) * SROW + kst]);
                    a[rr] = fma4(w3, xv, a[rr]);
                }
            }
            #pragma unroll
            for (int rr = 0; rr < 4; ++rr)
                pTmp[ks * 256 + c * 32 + (rgl + 8 * rr)] = a[rr];
            __syncthreads();

            int o = cR * 32 + riR;
            float sH2 = pTmp[o] + pTmp[o + 256] + pTmp[o + 512] + pTmp[o + 768];
            float ht = tanhf(hx + sH2 + bH);
            float hn = (1.f - zv) * hp + zv * ht;
            gstore(hOwn + (rowbase + riR) * 512 + cgR, hn);
        }

        flag_barrier(flags, slot, tid, (unsigned)(2 * s + 2));
    }
}

__global__ __launch_bounds__(128) void gru_fc(
    const float* __restrict__ h1f, const float* __restrict__ fcW,
    const float* __restrict__ fcb, float* __restrict__ out)
{
    int tid = threadIdx.x;
    int b = tid >> 1, cc = tid & 1;
    const float* hrow = h1f + b * 512;
    const float* wrow = fcW + cc * 512;
    float acc = 0.f;
    #pragma unroll 4
    for (int k = 0; k < 512; k += 4) {
        float4 hv = *(const float4*)(hrow + k);
        float4 wv = *(const float4*)(wrow + k);
        acc = fmaf(hv.x, wv.x, fmaf(hv.y, wv.y, fmaf(hv.z, wv.z, fmaf(hv.w, wv.w, acc))));
    }
    out[b * 2 + cc] = acc + fcb[cc];
}

extern "C" void kernel_launch(void* const* d_in, const int* in_sizes, int n_in,
                              void* d_out, int out_size, void* d_ws, size_t ws_size,
                              hipStream_t stream) {
    const int* tokens = (const int*)d_in[0];
    const float* emb = (const float*)d_in[1];
    const float* Wr0 = (const float*)d_in[2];  const float* br0 = (const float*)d_in[3];
    const float* Wz0 = (const float*)d_in[4];  const float* bz0 = (const float*)d_in[5];
    const float* Wh0 = (const float*)d_in[6];  const float* bh0 = (const float*)d_in[7];
    const float* Wr1 = (const float*)d_in[8];  const float* br1 = (const float*)d_in[9];
    const float* Wz1 = (const float*)d_in[10]; const float* bz1 = (const float*)d_in[11];
    const float* Wh1 = (const float*)d_in[12]; const float* bh1 = (const float*)d_in[13];
    const float* fcW = (const float*)d_in[14]; const float* fcb = (const float*)d_in[15];
    float* ws = (float*)d_ws;

    hipMemsetAsync(d_ws, 0, WS_BYTES, stream);

    gru_main<<<256, 256, 0, stream>>>(tokens, emb, Wr0, br0, Wz0, bz0, Wh0, bh0,
                                      Wr1, br1, Wz1, bz1, Wh1, bh1, ws);
    gru_fc<<<1, 128, 0, stream>>>(ws + H1_OFF, fcW, fcb, (float*)d_out);
}

// Round 6
// 21983.403 us; speedup vs baseline: 2.9372x; 1.8551x over previous
//
#include <hip/hip_runtime.h>
#include <hip/hip_bf16.h>
#include <math.h>

// ws layout (floats)
#define H0_OFF   0            // [64][512]
#define H1_OFF   32768        // [64][512]
#define RH0_OFF  65536        // [64][512]
#define RH1_OFF  98304        // [64][512]
#define FLG_OFF  131072       // u32 arr[256] + go[8 x 32-stride]
#define WS_FLOATS (131072 + 512)
#define WS_BYTES  (WS_FLOATS * 4)

// LDS row stride (words). 516 % 32 == 4: rows rgl=0..7 land on 8 distinct
// bank-quads (4*rgl mod 32 = {0,4,...,28}) -> b128 state reads conflict-free.
// 516 % 4 == 0 keeps 16 B alignment. Single 32x516 buffer + pTmp = 78,336 B
// <= 80 KB so TWO wgs fit per CU (needed for the 257th coordinator wg).
#define SROW 516

__device__ __forceinline__ void gstore(float* p, float v) {
    __hip_atomic_store(p, v, __ATOMIC_RELAXED, __HIP_MEMORY_SCOPE_AGENT);
}
__device__ __forceinline__ unsigned gloadU(const unsigned* p) {
    return __hip_atomic_load(p, __ATOMIC_RELAXED, __HIP_MEMORY_SCOPE_AGENT);
}
__device__ __forceinline__ void gstoreU(unsigned* p, unsigned v) {
    __hip_atomic_store(p, v, __ATOMIC_RELAXED, __HIP_MEMORY_SCOPE_AGENT);
}
__device__ __forceinline__ float fma4(float4 w, float4 x, float a) {
    a = fmaf(w.x, x.x, a); a = fmaf(w.y, x.y, a);
    a = fmaf(w.z, x.z, a); a = fmaf(w.w, x.w, a);
    return a;
}

// Coherent (L3-direct) 16B loads: 64 KB region -> LDS, 16 loads/thread.
// asm is required for sc0 sc1 on a b128 load; values NOT ready until the
// vmcnt(0) drain, so issue all, drain once, then write LDS.
__device__ __forceinline__ void stage64_sc(float* __restrict__ buf,
                                           const float* __restrict__ src, int tid) {
    float4 t[16];
    #pragma unroll
    for (int i = 0; i < 16; ++i) {
        const float* p = src + 4 * tid + 1024 * i;
        asm volatile("global_load_dwordx4 %0, %1, off sc0 sc1"
                     : "=&v"(t[i]) : "v"(p) : "memory");
    }
    asm volatile("s_waitcnt vmcnt(0)" ::: "memory");
    #pragma unroll
    for (int i = 0; i < 16; ++i) {
        int f4i = tid + 256 * i;
        int row = f4i >> 7, col4 = f4i & 127;
        *(float4*)&buf[row * SROW + col4 * 4] = t[i];
    }
}

__global__ __launch_bounds__(256) void gru_main(
    const int* __restrict__ tokens, const float* __restrict__ emb,
    const float* __restrict__ Wr0, const float* __restrict__ br0,
    const float* __restrict__ Wz0, const float* __restrict__ bz0,
    const float* __restrict__ Wh0, const float* __restrict__ bh0,
    const float* __restrict__ Wr1, const float* __restrict__ br1,
    const float* __restrict__ Wz1, const float* __restrict__ bz1,
    const float* __restrict__ Wh1, const float* __restrict__ bh1,
    float* __restrict__ ws)
{
    const int blk = blockIdx.x;
    const int tid = threadIdx.x;
    unsigned* arr = (unsigned*)(ws + FLG_OFF);
    unsigned* go  = arr + 256;

    // ---------------- coordinator wg: barrier engine only ----------------
    if (blk == 256) {
        if (tid >= 64) return;
        for (unsigned tag = 1; tag <= 2050; ++tag) {
            for (;;) {
                unsigned a0 = gloadU(arr + tid);
                unsigned a1 = gloadU(arr + 64 + tid);
                unsigned a2 = gloadU(arr + 128 + tid);
                unsigned a3 = gloadU(arr + 192 + tid);
                bool ok = ((int)(a0 - tag) >= 0) && ((int)(a1 - tag) >= 0) &&
                          ((int)(a2 - tag) >= 0) && ((int)(a3 - tag) >= 0);
                if (__ballot(ok) == ~0ull) break;
                __builtin_amdgcn_s_sleep(2);
            }
            if (tid < 8) gstoreU(go + tid * 32, tag);   // per-XCD go lines
        }
        return;
    }

    // ---------------- compute wgs ----------------
    // XCD = blk%8 = rg*4 + jl -> per-XCD weight footprint 2.75 MB (L2-resident,
    // validated by R5's FETCH_SIZE).
    const int rg    = (blk >> 2) & 1;
    const int jl    = blk & 3;
    const int jh    = (blk >> 3) & 15;
    const int layer = blk >> 7;
    const int j     = jh * 4 + jl;
    const int ks    = tid >> 6;               // wave = k-slice
    const int lane  = tid & 63;
    const int c     = lane >> 3;
    const int rgl   = lane & 7;
    const int rowbase = rg * 32;
    const int cg    = j * 8 + c;
    const int cR    = tid >> 5;               // reducer col
    const int riR   = tid & 31;               // reducer row
    const int cgR   = j * 8 + cR;
    const int xcd   = blk & 7;

    const int S1 = layer ? 512 : 256;
    const float* wrRow = (layer ? Wr1 : Wr0) + (size_t)cg * (S1 + 512);
    const float* wzRow = (layer ? Wz1 : Wz0) + (size_t)cg * (S1 + 512);
    const float* whRow = (layer ? Wh1 : Wh0) + (size_t)cg * (S1 + 512);
    const float bR = (layer ? br1 : br0)[cgR];
    const float bZ = (layer ? bz1 : bz0)[cgR];
    const float bH = (layer ? bh1 : bh0)[cgR];

    float* hOwn  = ws + (layer ? H1_OFF : H0_OFF);
    float* rhOwn = ws + (layer ? RH1_OFF : RH0_OFF);
    const float* hIn = ws + H0_OFF;

    __shared__ float bufA[32 * SROW];   // 66,048 B
    __shared__ float pTmp[3 * 4 * 256]; // 12,288 B

    const int k1 = ks * (S1 >> 2);      // seg1 wave base
    const int k2s = ks * 128;           // seg2 wave base (state coords)

    for (int s = 0; s <= 1024; ++s) {
        const bool act = layer ? (s >= 1) : (s < 1024);
        float zv = 0.f, hp = 0.f, hx = 0.f;

        if (act) {
            // ---- stage seg1 ----
            if (layer) {
                stage64_sc(bufA, hIn + rowbase * 512, tid);
            } else {
                #pragma unroll
                for (int q = 0; q < 8; ++q) {
                    int f4i = tid + 256 * q;
                    int row = f4i >> 6, col4 = f4i & 63;
                    int tok = tokens[(rowbase + row) * 1024 + s];
                    float4 v = *(const float4*)(emb + (size_t)tok * 256 + col4 * 4);
                    *(float4*)&bufA[row * SROW + col4 * 4] = v;
                }
            }
            __syncthreads();

            // ---- dot seg1: all 3 gates ----
            float aR[4] = {0,0,0,0}, aZ[4] = {0,0,0,0}, aH[4] = {0,0,0,0};
            const int nq1 = S1 >> 4;   // 16 (L0) / 32 (L1)
            #pragma unroll 4
            for (int i = 0; i < nq1; ++i) {
                int kk = k1 + 4 * i;
                float4 w1 = *(const float4*)(wrRow + kk);
                float4 w2 = *(const float4*)(wzRow + kk);
                float4 w3 = *(const float4*)(whRow + kk);
                #pragma unroll
                for (int rr = 0; rr < 4; ++rr) {
                    float4 xv = *(const float4*)(&bufA[(rgl + 8 * rr) * SROW + kk]);
                    aR[rr] = fma4(w1, xv, aR[rr]);
                    aZ[rr] = fma4(w2, xv, aZ[rr]);
                    aH[rr] = fma4(w3, xv, aH[rr]);
                }
            }
            __syncthreads();            // all waves done reading seg1

            // ---- restage: own h_prev ----
            stage64_sc(bufA, hOwn + rowbase * 512, tid);
            __syncthreads();

            // ---- dot seg2: r,z ----
            #pragma unroll 4
            for (int i = 0; i < 32; ++i) {
                int kw = S1 + k2s + 4 * i, kst = k2s + 4 * i;
                float4 w1 = *(const float4*)(wrRow + kw);
                float4 w2 = *(const float4*)(wzRow + kw);
                #pragma unroll
                for (int rr = 0; rr < 4; ++rr) {
                    float4 xv = *(const float4*)(&bufA[(rgl + 8 * rr) * SROW + kst]);
                    aR[rr] = fma4(w1, xv, aR[rr]);
                    aZ[rr] = fma4(w2, xv, aZ[rr]);
                }
            }
            #pragma unroll
            for (int rr = 0; rr < 4; ++rr) {
                int o = ks * 256 + c * 32 + (rgl + 8 * rr);
                pTmp[o]        = aR[rr];
                pTmp[1024 + o] = aZ[rr];
                pTmp[2048 + o] = aH[rr];
            }
            __syncthreads();

            int o = cR * 32 + riR;
            float sR = pTmp[o] + pTmp[o + 256] + pTmp[o + 512] + pTmp[o + 768];
            float sZ = pTmp[1024 + o] + pTmp[1280 + o] + pTmp[1536 + o] + pTmp[1792 + o];
            float sH = pTmp[2048 + o] + pTmp[2304 + o] + pTmp[2560 + o] + pTmp[2816 + o];
            float rv = 1.f / (1.f + expf(-(sR + bR)));
            zv = 1.f / (1.f + expf(-(sZ + bZ)));
            hx = sH;
            hp = bufA[riR * SROW + cgR];          // own h_prev[row, col]
            gstore(rhOwn + (rowbase + riR) * 512 + cgR, rv * hp);
        }

        // ---- P1 barrier ----
        __syncthreads();
        if (tid == 0) {
            gstoreU(arr + blk, (unsigned)(2 * s + 1));
            const unsigned* gw = go + xcd * 32;
            while ((int)(gloadU(gw) - (unsigned)(2 * s + 1)) < 0)
                __builtin_amdgcn_s_sleep(2);
        }
        __syncthreads();

        if (act) {
            // ---- stage rh ----
            stage64_sc(bufA, rhOwn + rowbase * 512, tid);
            __syncthreads();

            // ---- dot: h-gate recurrent ----
            float a[4] = {0,0,0,0};
            #pragma unroll 4
            for (int i = 0; i < 32; ++i) {
                int kw = S1 + k2s + 4 * i, kst = k2s + 4 * i;
                float4 w3 = *(const float4*)(whRow + kw);
                #pragma unroll
                for (int rr = 0; rr < 4; ++rr) {
                    float4 xv = *(const float4*)(&bufA[(rgl + 8 * rr) * SROW + kst]);
                    a[rr] = fma4(w3, xv, a[rr]);
                }
            }
            #pragma unroll
            for (int rr = 0; rr < 4; ++rr)
                pTmp[ks * 256 + c * 32 + (rgl + 8 * rr)] = a[rr];
            __syncthreads();

            int o = cR * 32 + riR;
            float sH2 = pTmp[o] + pTmp[o + 256] + pTmp[o + 512] + pTmp[o + 768];
            float ht = tanhf(hx + sH2 + bH);
            float hn = (1.f - zv) * hp + zv * ht;
            gstore(hOwn + (rowbase + riR) * 512 + cgR, hn);
        }

        // ---- P2 barrier ----
        __syncthreads();
        if (tid == 0) {
            gstoreU(arr + blk, (unsigned)(2 * s + 2));
            const unsigned* gw = go + xcd * 32;
            while ((int)(gloadU(gw) - (unsigned)(2 * s + 2)) < 0)
                __builtin_amdgcn_s_sleep(2);
        }
        __syncthreads();
    }
}

__global__ __launch_bounds__(128) void gru_fc(
    const float* __restrict__ h1f, const float* __restrict__ fcW,
    const float* __restrict__ fcb, float* __restrict__ out)
{
    int tid = threadIdx.x;
    int b = tid >> 1, cc = tid & 1;
    const float* hrow = h1f + b * 512;
    const float* wrow = fcW + cc * 512;
    float acc = 0.f;
    #pragma unroll 4
    for (int k = 0; k < 512; k += 4) {
        float4 hv = *(const float4*)(hrow + k);
        float4 wv = *(const float4*)(wrow + k);
        acc = fmaf(hv.x, wv.x, fmaf(hv.y, wv.y, fmaf(hv.z, wv.z, fmaf(hv.w, wv.w, acc))));
    }
    out[b * 2 + cc] = acc + fcb[cc];
}

extern "C" void kernel_launch(void* const* d_in, const int* in_sizes, int n_in,
                              void* d_out, int out_size, void* d_ws, size_t ws_size,
                              hipStream_t stream) {
    const int* tokens = (const int*)d_in[0];
    const float* emb = (const float*)d_in[1];
    const float* Wr0 = (const float*)d_in[2];  const float* br0 = (const float*)d_in[3];
    const float* Wz0 = (const float*)d_in[4];  const float* bz0 = (const float*)d_in[5];
    const float* Wh0 = (const float*)d_in[6];  const float* bh0 = (const float*)d_in[7];
    const float* Wr1 = (const float*)d_in[8];  const float* br1 = (const float*)d_in[9];
    const float* Wz1 = (const float*)d_in[10]; const float* bz1 = (const float*)d_in[11];
    const float* Wh1 = (const float*)d_in[12]; const float* bh1 = (const float*)d_in[13];
    const float* fcW = (const float*)d_in[14]; const float* fcb = (const float*)d_in[15];
    float* ws = (float*)d_ws;

    hipMemsetAsync(d_ws, 0, WS_BYTES, stream);

    gru_main<<<257, 256, 0, stream>>>(tokens, emb, Wr0, br0, Wz0, bz0, Wh0, bh0,
                                      Wr1, br1, Wz1, bz1, Wh1, bh1, ws);
    gru_fc<<<1, 128, 0, stream>>>(ws + H1_OFF, fcW, fcb, (float*)d_out);
}

// Round 7
// 21542.747 us; speedup vs baseline: 2.9973x; 1.0205x over previous
//
#include <hip/hip_runtime.h>
#include <hip/hip_bf16.h>
#include <math.h>

// ws layout (floats)
#define H0_OFF   0            // [64][512]
#define H1_OFF   32768        // [64][512]
#define RH0_OFF  65536        // [64][512]
#define RH1_OFF  98304        // [64][512]
#define FLG_OFF  131072       // u32 arr[256] + go[8 x 32-stride]
#define WS_FLOATS (131072 + 512)
#define WS_BYTES  (WS_FLOATS * 4)

// LDS row stride (words). 516 % 32 == 4: rows rgl=0..7 -> 8 distinct bank
// quads -> conflict-free b128 state reads. 516 % 4 == 0 keeps 16B alignment.
#define SROW 516

__device__ __forceinline__ void gstore(float* p, float v) {
    __hip_atomic_store(p, v, __ATOMIC_RELAXED, __HIP_MEMORY_SCOPE_AGENT);
}
__device__ __forceinline__ unsigned gloadU(const unsigned* p) {
    return __hip_atomic_load(p, __ATOMIC_RELAXED, __HIP_MEMORY_SCOPE_AGENT);
}
__device__ __forceinline__ void gstoreU(unsigned* p, unsigned v) {
    __hip_atomic_store(p, v, __ATOMIC_RELAXED, __HIP_MEMORY_SCOPE_AGENT);
}
__device__ __forceinline__ float fma4(float4 w, float4 x, float a) {
    a = fmaf(w.x, x.x, a); a = fmaf(w.y, x.y, a);
    a = fmaf(w.z, x.z, a); a = fmaf(w.w, x.w, a);
    return a;
}

// Issue 16 coherent b128 loads (64 KB region across 256 threads). Values are
// NOT valid until a vmcnt drain.
__device__ __forceinline__ void issue16(float4 t[16], const float* __restrict__ src, int tid) {
    #pragma unroll
    for (int i = 0; i < 16; ++i) {
        const float* p = src + 4 * tid + 1024 * i;
        asm volatile("global_load_dwordx4 %0, %1, off sc0 sc1"
                     : "=&v"(t[i]) : "v"(p) : "memory");
    }
}
__device__ __forceinline__ void drain_all() {
    asm volatile("s_waitcnt vmcnt(0)" ::: "memory");
}
// Wait until only the 16 NEWEST vmem ops remain outstanding (FIFO): completes
// everything issued before them. Later compiler-emitted waits can only be
// more conservative (they force extra completion), never unsafe.
__device__ __forceinline__ void drain_keep16() {
    asm volatile("s_waitcnt vmcnt(16)" ::: "memory");
}
__device__ __forceinline__ void lds_write16(float* __restrict__ buf, const float4 t[16], int tid) {
    #pragma unroll
    for (int i = 0; i < 16; ++i) {
        int f4i = tid + 256 * i;
        int row = f4i >> 7, col4 = f4i & 127;
        *(float4*)&buf[row * SROW + col4 * 4] = t[i];
    }
}

__global__ __launch_bounds__(320, 1) void gru_main(
    const int* __restrict__ tokens, const float* __restrict__ emb,
    const float* __restrict__ Wr0, const float* __restrict__ br0,
    const float* __restrict__ Wz0, const float* __restrict__ bz0,
    const float* __restrict__ Wh0, const float* __restrict__ bh0,
    const float* __restrict__ Wr1, const float* __restrict__ br1,
    const float* __restrict__ Wz1, const float* __restrict__ bz1,
    const float* __restrict__ Wh1, const float* __restrict__ bh1,
    float* __restrict__ ws)
{
    const int blk = blockIdx.x;
    const int tid = threadIdx.x;
    const bool comp = tid < 256;          // waves 0-3 compute; wave 4 = barrier duty (wg0)
    unsigned* arr = (unsigned*)(ws + FLG_OFF);
    unsigned* go  = arr + 256;

    // XCD = blk%8 = rg*4 + jl -> per-XCD weight footprint 2.75 MB (L2-resident).
    const int rg    = (blk >> 2) & 1;
    const int jl    = blk & 3;
    const int jh    = (blk >> 3) & 15;
    const int layer = blk >> 7;
    const int j     = jh * 4 + jl;
    const int xcd   = blk & 7;
    const int ks    = (tid >> 6) & 3;     // wave = k-slice (compute waves)
    const int lane  = tid & 63;
    const int c     = lane >> 3;
    const int rgl   = lane & 7;
    const int rowbase = rg * 32;
    const int cg    = j * 8 + c;
    const int cR    = (tid >> 5) & 7;     // reducer col
    const int riR   = tid & 31;           // reducer row
    const int cgR   = j * 8 + cR;

    const int S1 = layer ? 512 : 256;
    const int K  = S1 + 512;
    const float* WrL = layer ? Wr1 : Wr0;
    const float* WzL = layer ? Wz1 : Wz0;
    const float* WhL = layer ? Wh1 : Wh0;
    const float* wrRow = WrL + (size_t)cg * K;
    const float* wzRow = WzL + (size_t)cg * K;
    const float* whRow = WhL + (size_t)cg * K;
    const float bR = (layer ? br1 : br0)[cgR];
    const float bZ = (layer ? bz1 : bz0)[cgR];
    const float bH = (layer ? bh1 : bh0)[cgR];

    float* hOwn  = ws + (layer ? H1_OFF : H0_OFF);
    float* rhOwn = ws + (layer ? RH1_OFF : RH0_OFF);
    const float* hIn = ws + H0_OFF;

    __shared__ float  bufA[32 * SROW];    // 66,048 B  (seg1 -> h_prev -> rh)
    __shared__ float  pTmp[3 * 1024];     // 12,288 B
    __shared__ float4 wLDS[3072];         // 49,152 B  seg2 weights [gate][chunk][col]

    // ---- one-time: seg2 weights (own 8 cols, 3 gates) -> LDS ----
    if (comp) {
        const float* Wb[3] = {WrL, WzL, WhL};
        for (int idx = tid; idx < 3072; idx += 256) {
            int g = idx >> 10, rem = idx & 1023, chunk = rem >> 3, c8 = rem & 7;
            wLDS[(g * 128 + chunk) * 8 + c8] =
                *(const float4*)(Wb[g] + (size_t)(j * 8 + c8) * K + S1 + 4 * chunk);
        }
    }

    const int k1  = ks * (S1 >> 2);       // seg1 wave base
    const int k2s = ks * 128;             // seg2 wave base (state coords)
    const int wch = ks * 32;              // seg2 wave base (wLDS chunk coords)

    for (int s = 0; s <= 1024; ++s) {
        const bool act = layer ? (s >= 1) : (s < 1024);
        float zv = 0.f, hp = 0.f, hx = 0.f;
        float aR[4] = {0,0,0,0}, aZ[4] = {0,0,0,0}, aH[4] = {0,0,0,0};
        float4 hpv[16];

        // ---- phase A: stage seg1 (drained) + prefetch h_prev (left in flight) ----
        if (act && comp) {
            if (layer) {
                float4 t[16];
                issue16(t, hIn + rowbase * 512, tid);     // oldest 16
                issue16(hpv, hOwn + rowbase * 512, tid);  // newest 16
                drain_keep16();                           // seg1 done, hpv in flight
                lds_write16(bufA, t, tid);
            } else {
                float4 t[8];
                #pragma unroll
                for (int q = 0; q < 8; ++q) {             // emb gather (oldest)
                    int f4i = tid + 256 * q;
                    int row = f4i >> 6, col4 = f4i & 63;
                    int tok = tokens[(rowbase + row) * 1024 + s];
                    t[q] = *(const float4*)(emb + (size_t)tok * 256 + col4 * 4);
                }
                issue16(hpv, hOwn + rowbase * 512, tid);  // newest 16
                drain_keep16();                           // emb done, hpv in flight
                #pragma unroll
                for (int q = 0; q < 8; ++q) {
                    int f4i = tid + 256 * q;
                    int row = f4i >> 6, col4 = f4i & 63;
                    *(float4*)&bufA[row * SROW + col4 * 4] = t[q];
                }
            }
        }
        __syncthreads();

        // ---- dot seg1 (weights stream from L2; h_prev loads still in flight) ----
        if (act && comp) {
            const int nq1 = S1 >> 4;
            #pragma unroll 4
            for (int i = 0; i < nq1; ++i) {
                int kk = k1 + 4 * i;
                float4 w1 = *(const float4*)(wrRow + kk);
                float4 w2 = *(const float4*)(wzRow + kk);
                float4 w3 = *(const float4*)(whRow + kk);
                #pragma unroll
                for (int rr = 0; rr < 4; ++rr) {
                    float4 xv = *(const float4*)(&bufA[(rgl + 8 * rr) * SROW + kk]);
                    aR[rr] = fma4(w1, xv, aR[rr]);
                    aZ[rr] = fma4(w2, xv, aZ[rr]);
                    aH[rr] = fma4(w3, xv, aH[rr]);
                }
            }
        }
        __syncthreads();                  // all waves done reading seg1

        if (act && comp) {
            drain_all();                  // h_prev arrived during seg1 dot
            lds_write16(bufA, hpv, tid);
        }
        __syncthreads();

        // ---- dot seg2: r,z from LDS weights ----
        if (act && comp) {
            #pragma unroll 4
            for (int i = 0; i < 32; ++i) {
                int kst = k2s + 4 * i;
                float4 w1 = wLDS[(wch + i) * 8 + c];
                float4 w2 = wLDS[(128 + wch + i) * 8 + c];
                #pragma unroll
                for (int rr = 0; rr < 4; ++rr) {
                    float4 xv = *(const float4*)(&bufA[(rgl + 8 * rr) * SROW + kst]);
                    aR[rr] = fma4(w1, xv, aR[rr]);
                    aZ[rr] = fma4(w2, xv, aZ[rr]);
                }
            }
            #pragma unroll
            for (int rr = 0; rr < 4; ++rr) {
                int o = ks * 256 + c * 32 + (rgl + 8 * rr);
                pTmp[o]        = aR[rr];
                pTmp[1024 + o] = aZ[rr];
                pTmp[2048 + o] = aH[rr];
            }
        }
        __syncthreads();

        // ---- reduce + activations + publish rh ----
        if (act && comp) {
            int o = cR * 32 + riR;
            float sR = pTmp[o] + pTmp[o + 256] + pTmp[o + 512] + pTmp[o + 768];
            float sZ = pTmp[1024 + o] + pTmp[1280 + o] + pTmp[1536 + o] + pTmp[1792 + o];
            float sH = pTmp[2048 + o] + pTmp[2304 + o] + pTmp[2560 + o] + pTmp[2816 + o];
            float rv = 1.f / (1.f + expf(-(sR + bR)));
            zv = 1.f / (1.f + expf(-(sZ + bZ)));
            hx = sH;
            hp = bufA[riR * SROW + cgR];          // bufA still holds h_prev
            gstore(rhOwn + (rowbase + riR) * 512 + cgR, rv * hp);
        }

        // ---- barrier 1 (tag 2s+1): wg0 wave4 coordinates ----
        {
            const unsigned tag = (unsigned)(2 * s + 1);
            __syncthreads();
            if (!comp) {
                if (blk == 0) {
                    const int l4 = tid - 256;
                    for (;;) {
                        unsigned a0 = gloadU(arr + l4), a1 = gloadU(arr + 64 + l4);
                        unsigned a2 = gloadU(arr + 128 + l4), a3 = gloadU(arr + 192 + l4);
                        bool ok = ((int)(a0 - tag) >= 0) && ((int)(a1 - tag) >= 0) &&
                                  ((int)(a2 - tag) >= 0) && ((int)(a3 - tag) >= 0);
                        if (__ballot(ok) == ~0ull) break;
                        __builtin_amdgcn_s_sleep(2);
                    }
                    if (l4 < 8) gstoreU(go + l4 * 32, tag);
                }
            } else if (tid == 0) {
                gstoreU(arr + blk, tag);
                while ((int)(gloadU(go + xcd * 32) - tag) < 0)
                    __builtin_amdgcn_s_sleep(2);
            }
            __syncthreads();
        }

        // ---- P2: stage rh, h-gate recurrent dot ----
        if (act && comp) {
            float4 t[16];
            issue16(t, rhOwn + rowbase * 512, tid);
            drain_all();
            lds_write16(bufA, t, tid);
        }
        __syncthreads();

        if (act && comp) {
            float a[4] = {0,0,0,0};
            #pragma unroll 4
            for (int i = 0; i < 32; ++i) {
                int kst = k2s + 4 * i;
                float4 w3 = wLDS[(256 + wch + i) * 8 + c];
                #pragma unroll
                for (int rr = 0; rr < 4; ++rr) {
                    float4 xv = *(const float4*)(&bufA[(rgl + 8 * rr) * SROW + kst]);
                    a[rr] = fma4(w3, xv, a[rr]);
                }
            }
            #pragma unroll
            for (int rr = 0; rr < 4; ++rr)
                pTmp[ks * 256 + c * 32 + (rgl + 8 * rr)] = a[rr];
        }
        __syncthreads();

        if (act && comp) {
            int o = cR * 32 + riR;
            float sH2 = pTmp[o] + pTmp[o + 256] + pTmp[o + 512] + pTmp[o + 768];
            float ht = tanhf(hx + sH2 + bH);
            float hn = (1.f - zv) * hp + zv * ht;
            gstore(hOwn + (rowbase + riR) * 512 + cgR, hn);
        }

        // ---- barrier 2 (tag 2s+2) ----
        {
            const unsigned tag = (unsigned)(2 * s + 2);
            __syncthreads();
            if (!comp) {
                if (blk == 0) {
                    const int l4 = tid - 256;
                    for (;;) {
                        unsigned a0 = gloadU(arr + l4), a1 = gloadU(arr + 64 + l4);
                        unsigned a2 = gloadU(arr + 128 + l4), a3 = gloadU(arr + 192 + l4);
                        bool ok = ((int)(a0 - tag) >= 0) && ((int)(a1 - tag) >= 0) &&
                                  ((int)(a2 - tag) >= 0) && ((int)(a3 - tag) >= 0);
                        if (__ballot(ok) == ~0ull) break;
                        __builtin_amdgcn_s_sleep(2);
                    }
                    if (l4 < 8) gstoreU(go + l4 * 32, tag);
                }
            } else if (tid == 0) {
                gstoreU(arr + blk, tag);
                while ((int)(gloadU(go + xcd * 32) - tag) < 0)
                    __builtin_amdgcn_s_sleep(2);
            }
            __syncthreads();
        }
    }
}

__global__ __launch_bounds__(128) void gru_fc(
    const float* __restrict__ h1f, const float* __restrict__ fcW,
    const float* __restrict__ fcb, float* __restrict__ out)
{
    int tid = threadIdx.x;
    int b = tid >> 1, cc = tid & 1;
    const float* hrow = h1f + b * 512;
    const float* wrow = fcW + cc * 512;
    float acc = 0.f;
    #pragma unroll 4
    for (int k = 0; k < 512; k += 4) {
        float4 hv = *(const float4*)(hrow + k);
        float4 wv = *(const float4*)(wrow + k);
        acc = fmaf(hv.x, wv.x, fmaf(hv.y, wv.y, fmaf(hv.z, wv.z, fmaf(hv.w, wv.w, acc))));
    }
    out[b * 2 + cc] = acc + fcb[cc];
}

extern "C" void kernel_launch(void* const* d_in, const int* in_sizes, int n_in,
                              void* d_out, int out_size, void* d_ws, size_t ws_size,
                              hipStream_t stream) {
    const int* tokens = (const int*)d_in[0];
    const float* emb = (const float*)d_in[1];
    const float* Wr0 = (const float*)d_in[2];  const float* br0 = (const float*)d_in[3];
    const float* Wz0 = (const float*)d_in[4];  const float* bz0 = (const float*)d_in[5];
    const float* Wh0 = (const float*)d_in[6];  const float* bh0 = (const float*)d_in[7];
    const float* Wr1 = (const float*)d_in[8];  const float* br1 = (const float*)d_in[9];
    const float* Wz1 = (const float*)d_in[10]; const float* bz1 = (const float*)d_in[11];
    const float* Wh1 = (const float*)d_in[12]; const float* bh1 = (const float*)d_in[13];
    const float* fcW = (const float*)d_in[14]; const float* fcb = (const float*)d_in[15];
    float* ws = (float*)d_ws;

    hipMemsetAsync(d_ws, 0, WS_BYTES, stream);

    gru_main<<<256, 320, 0, stream>>>(tokens, emb, Wr0, br0, Wz0, bz0, Wh0, bh0,
                                      Wr1, br1, Wz1, bz1, Wh1, bh1, ws);
    gru_fc<<<1, 128, 0, stream>>>(ws + H1_OFF, fcW, fcb, (float*)d_out);
}